// Round 14
// baseline (298.014 us; speedup 1.0000x reference)
//
#include <hip/hip_runtime.h>
#include <math.h>

// B=2, S=64, C=64, NH=8, H=W=32, M1=M2=16 (256 modes), mode m=p*16+q.
// lambda folded into Pq planes, mu folded into Pv planes (exact pow2 scales);
// DC imag planes of Pq/Pv zeroed (valid since Xi[m=0]==0 exactly).
// R14 = R13 + register prefetch (T14) of next-iteration W/At in scores and
// vpath (isolated; no setprio, no other changes).

#define PI_F 3.14159265358979323846f

typedef _Float16 f16;
typedef f16 f16x8 __attribute__((ext_vector_type(8)));
typedef f16 f16x4 __attribute__((ext_vector_type(4)));
typedef float f32x4 __attribute__((ext_vector_type(4)));

#define MFMA(a, b, c) __builtin_amdgcn_mfma_f32_16x16x32_f16(a, b, c, 0, 0, 0)

__device__ __forceinline__ int swz128(int row, int slot) {
  return (row << 7) + (((slot) ^ (row & 7)) << 4);
}
__device__ __forceinline__ int swzel(int row, int col) {
  return (row << 7) + ((((col) >> 3) ^ (row & 7)) << 4) + (((col) & 7) << 1);
}

// ---------------- dft body (R5-proven) --------------------------------------
__device__ void dft_body(char* sm, int f, int tid, const float* __restrict__ seq,
                         f16* __restrict__ Xr, f16* __restrict__ Xi) {
  float(*fld)[33] = (float(*)[33])sm;            // 4224 B
  float2(*tb)[17] = (float2(*)[17])(sm + 4224);  // 4352 B
  float2* tw = (float2*)(sm + 8576);             // 256 B
  if (tid < 32) {
    float a = (2.0f * PI_F / 32.0f) * (float)tid;
    tw[tid] = make_float2(cosf(a), sinf(a));
  }
  const float4* s4 = (const float4*)(seq + (size_t)f * 1024);
  float4 v = s4[tid];
  int x0 = tid >> 3, y0 = (tid & 7) * 4;
  fld[x0][y0 + 0] = v.x; fld[x0][y0 + 1] = v.y;
  fld[x0][y0 + 2] = v.z; fld[x0][y0 + 3] = v.w;
  __syncthreads();
  for (int o = tid; o < 512; o += 256) {
    int x = o >> 4, q = o & 15;
    float re = 0.f, im = 0.f;
#pragma unroll
    for (int y = 0; y < 32; ++y) {
      float val = fld[x][y];
      float2 w = tw[(q * y) & 31];
      re = fmaf(val, w.x, re);
      im = fmaf(val, -w.y, im);
    }
    tb[x][q] = make_float2(re, im);
  }
  __syncthreads();
  int p = tid >> 4, q = tid & 15;
  float re = 0.f, im = 0.f;
#pragma unroll
  for (int x = 0; x < 32; ++x) {
    float2 t = tb[x][q];
    float2 w = tw[(p * x) & 31];
    re += w.x * t.x + w.y * t.y;
    im += w.x * t.y - w.y * t.x;
  }
  int b = f >> 12;
  int si = f & 4095;
  size_t o = (size_t)(b * 256 + tid) * 4096 + si;
  Xr[o] = (f16)re;
  Xi[o] = (f16)im;
}

// ---------------- repack body (R9: R5 shape + bank swizzle) ----------------
__device__ void repack_body(char* sm, int gid, int tid,
                            const float2* __restrict__ wq,
                            const float2* __restrict__ wk,
                            const float2* __restrict__ wv,
                            const float2* __restrict__ wo,
                            f16* __restrict__ Pqr, f16* __restrict__ Pqi,
                            f16* __restrict__ Pkr, f16* __restrict__ Pki,
                            f16* __restrict__ Pvr, f16* __restrict__ Pvi,
                            f16* __restrict__ Por, f16* __restrict__ Poi) {
  f16(*tR)[72] = (f16(*)[72])sm;           // 9216 B
  f16(*tI)[72] = (f16(*)[72])(sm + 9216);  // 9216 B
  int tsel = gid >> 11, r = gid & 2047;
  const float2* in;
  f16 *oR, *oI;
  int m0 = (r & 3) * 64, a0, bb, A, B;
  bool scaled = (tsel == 0) || (tsel == 2);
  if (tsel == 3) {
    in = wo; oR = Por; oI = Poi;
    a0 = ((r >> 2) & 7) * 64; bb = r >> 5; A = 512; B = 64;
  } else {
    a0 = 0; bb = r >> 2; A = 64; B = 512;
    in = (tsel == 0) ? wq : (tsel == 1) ? wk : wv;
    oR = (tsel == 0) ? Pqr : (tsel == 1) ? Pkr : Pvr;
    oI = (tsel == 0) ? Pqi : (tsel == 1) ? Pki : Pvi;
  }
  const float4* in4 = (const float4*)in;
  for (int k = tid; k < 2048; k += 256) {
    int ai = k >> 5, mj = k & 31;
    float4 v = in4[((size_t)(a0 + ai) * B + bb) * 128 + (m0 >> 1) + mj];
    int sw = (mj & 7) << 3;
    tR[2 * mj + 0][ai ^ sw] = (f16)v.x;
    tI[2 * mj + 0][ai ^ sw] = (f16)v.y;
    tR[2 * mj + 1][ai ^ sw] = (f16)v.z;
    tI[2 * mj + 1][ai ^ sw] = (f16)v.w;
  }
  __syncthreads();
  for (int k = tid; k < 1024; k += 256) {
    int pl = k >> 9, s = k & 511;
    int mi = s >> 3, a8 = (s & 7) * 8;
    int sw = ((mi >> 1) & 7) << 3;
    f16x8 v = pl ? *(const f16x8*)&tI[mi][a8 ^ sw]
                 : *(const f16x8*)&tR[mi][a8 ^ sw];
    int mode = m0 + mi;
    if (scaled) {
      f16 scl = (mode == 0) ? (f16)1.0f
                            : (((mode & 15) == 0) ? (f16)0.5f : (f16)2.0f);
      v = v * scl;
      if (pl && mode == 0) v = (f16x8)(f16)0.0f;
    }
    f16* dst = pl ? oI : oR;
    *(f16x8*)&dst[(size_t)mode * 32768 + (size_t)bb * A + a0 + a8] = v;
  }
}

// ---------------- K-mega: repack (identity order) ∪ dft --------------------
__global__ __launch_bounds__(256) void k_mega(
    const float* __restrict__ seq, f16* __restrict__ Xr, f16* __restrict__ Xi,
    const float2* __restrict__ wq, const float2* __restrict__ wk,
    const float2* __restrict__ wv, const float2* __restrict__ wo,
    f16* __restrict__ Pqr, f16* __restrict__ Pqi, f16* __restrict__ Pkr,
    f16* __restrict__ Pki, f16* __restrict__ Pvr, f16* __restrict__ Pvi,
    f16* __restrict__ Por, f16* __restrict__ Poi) {
  __shared__ __align__(16) char sm[18432];
  int bx = blockIdx.x, tid = threadIdx.x;
  if (bx < 8192) {
    repack_body(sm, bx, tid, wq, wk, wv, wo, Pqr, Pqi, Pkr, Pki, Pvr, Pvi,
                Por, Poi);
  } else {
    dft_body(sm, bx - 8192, tid, seq, Xr, Xi);
  }
}

// ---------------- K2: MFMA scores, b-merged + T14 W prefetch ---------------
__global__ __launch_bounds__(256, 2) void k_scores_m(
    const f16* __restrict__ Xr, const f16* __restrict__ Xi,
    const f16* __restrict__ Qwr, const f16* __restrict__ Qwi,
    const f16* __restrict__ Kwr, const f16* __restrict__ Kwi,
    float* __restrict__ scores) {
  __shared__ __align__(16) unsigned char smem[65536];
  const int P_WQR = 0, P_WQI = 8192, P_WKR = 16384, P_WKI = 24576;
  const int P_QR = 32768, P_QI = 40960, P_KR = 49152, P_KI = 57344;
  int tid = threadIdx.x;
  int w = tid >> 6, lane = tid & 63, r = lane & 15, g = lane >> 4;
  int wr = w >> 1, wc = w & 1;
  int chunk = blockIdx.x, h = blockIdx.y;
  float4 Wst[8];
  auto LOADW = [&](int m) {
    const float4* gqr = (const float4*)Qwr + (size_t)m * 4096 + h * 512;
    const float4* gqi = (const float4*)Qwi + (size_t)m * 4096 + h * 512;
    const float4* gkr = (const float4*)Kwr + (size_t)m * 4096 + h * 512;
    const float4* gki = (const float4*)Kwi + (size_t)m * 4096 + h * 512;
    Wst[0] = gqr[tid]; Wst[1] = gqr[tid + 256];
    Wst[2] = gqi[tid]; Wst[3] = gqi[tid + 256];
    Wst[4] = gkr[tid]; Wst[5] = gkr[tid + 256];
    Wst[6] = gki[tid]; Wst[7] = gki[tid + 256];
  };
  f32x4 S[2][2][2] = {};  // [b][rt][ct]
  LOADW(chunk * 4);
  for (int mm = 0; mm < 4; ++mm) {
    int m = chunk * 4 + mm;
    // write prefetched regs -> LDS (W planes free: all reads behind barriers)
#pragma unroll
    for (int it = 0; it < 2; ++it) {
      int s = tid + it * 256;
      int lo = swz128(s >> 3, s & 7);
      *(float4*)(smem + P_WQR + lo) = Wst[0 + it];
      *(float4*)(smem + P_WQI + lo) = Wst[2 + it];
      *(float4*)(smem + P_WKR + lo) = Wst[4 + it];
      *(float4*)(smem + P_WKI + lo) = Wst[6 + it];
    }
    __syncthreads();
    if (mm < 3) LOADW(m + 1);  // fly under Q/K/S of both b
#pragma unroll
    for (int b = 0; b < 2; ++b) {
      const f16x8* xr8 = (const f16x8*)Xr + (size_t)(b * 256 + m) * 512;
      const f16x8* xi8 = (const f16x8*)Xi + (size_t)(b * 256 + m) * 512;
      f16x8 axr[2][2], axi[2][2];
#pragma unroll
      for (int rt = 0; rt < 2; ++rt)
#pragma unroll
        for (int kt = 0; kt < 2; ++kt) {
          int idx = (32 * wr + rt * 16 + r) * 8 + kt * 4 + g;
          axr[rt][kt] = xr8[idx];
          axi[rt][kt] = xi8[idx];
        }
      // ---- Q = X*Wq (lambda pre-folded; DC imag exact-zero) ----
      {
        f32x4 cr[2][2] = {}, ci[2][2] = {};
#pragma unroll
        for (int ct = 0; ct < 2; ++ct)
#pragma unroll
          for (int kt = 0; kt < 2; ++kt) {
            int lo = swz128(32 * wc + ct * 16 + r, kt * 4 + g);
            f16x8 bwr = *(const f16x8*)(smem + P_WQR + lo);
            f16x8 bwi = *(const f16x8*)(smem + P_WQI + lo);
            f16x8 bwiN = -bwi;
#pragma unroll
            for (int rt = 0; rt < 2; ++rt) {
              cr[rt][ct] = MFMA(axr[rt][kt], bwr, cr[rt][ct]);
              cr[rt][ct] = MFMA(axi[rt][kt], bwiN, cr[rt][ct]);
              ci[rt][ct] = MFMA(axr[rt][kt], bwi, ci[rt][ct]);
              ci[rt][ct] = MFMA(axi[rt][kt], bwr, ci[rt][ct]);
            }
          }
#pragma unroll
        for (int rt = 0; rt < 2; ++rt)
#pragma unroll
          for (int ct = 0; ct < 2; ++ct)
#pragma unroll
            for (int j = 0; j < 4; ++j) {
              int row = 32 * wr + rt * 16 + g * 4 + j;
              int col = 32 * wc + ct * 16 + r;
              *(f16*)(smem + P_QR + swzel(row, col)) = (f16)cr[rt][ct][j];
              *(f16*)(smem + P_QI + swzel(row, col)) = (f16)ci[rt][ct][j];
            }
      }
      // ---- K = X*Wk ----
      {
        f32x4 cr[2][2] = {}, ci[2][2] = {};
#pragma unroll
        for (int ct = 0; ct < 2; ++ct)
#pragma unroll
          for (int kt = 0; kt < 2; ++kt) {
            int lo = swz128(32 * wc + ct * 16 + r, kt * 4 + g);
            f16x8 bwr = *(const f16x8*)(smem + P_WKR + lo);
            f16x8 bwi = *(const f16x8*)(smem + P_WKI + lo);
            f16x8 bwiN = -bwi;
#pragma unroll
            for (int rt = 0; rt < 2; ++rt) {
              cr[rt][ct] = MFMA(axr[rt][kt], bwr, cr[rt][ct]);
              cr[rt][ct] = MFMA(axi[rt][kt], bwiN, cr[rt][ct]);
              ci[rt][ct] = MFMA(axr[rt][kt], bwi, ci[rt][ct]);
              ci[rt][ct] = MFMA(axi[rt][kt], bwr, ci[rt][ct]);
            }
          }
#pragma unroll
        for (int rt = 0; rt < 2; ++rt)
#pragma unroll
          for (int ct = 0; ct < 2; ++ct)
#pragma unroll
            for (int j = 0; j < 4; ++j) {
              int row = 32 * wr + rt * 16 + g * 4 + j;
              int col = 32 * wc + ct * 16 + r;
              *(f16*)(smem + P_KR + swzel(row, col)) = (f16)cr[rt][ct][j];
              *(f16*)(smem + P_KI + swzel(row, col)) = (f16)ci[rt][ct][j];
            }
      }
      __syncthreads();
      // ---- S[b] += Qr*Kr^T + Qi*Ki^T ----
      {
        f16x8 aqr[2][2], aqi[2][2];
#pragma unroll
        for (int rt = 0; rt < 2; ++rt)
#pragma unroll
          for (int kt = 0; kt < 2; ++kt) {
            int lo = swz128(32 * wr + rt * 16 + r, kt * 4 + g);
            aqr[rt][kt] = *(const f16x8*)(smem + P_QR + lo);
            aqi[rt][kt] = *(const f16x8*)(smem + P_QI + lo);
          }
#pragma unroll
        for (int ct = 0; ct < 2; ++ct)
#pragma unroll
          for (int kt = 0; kt < 2; ++kt) {
            int lo = swz128(32 * wc + ct * 16 + r, kt * 4 + g);
            f16x8 bkr = *(const f16x8*)(smem + P_KR + lo);
            f16x8 bki = *(const f16x8*)(smem + P_KI + lo);
#pragma unroll
            for (int rt = 0; rt < 2; ++rt) {
              S[b][rt][ct] = MFMA(aqr[rt][kt], bkr, S[b][rt][ct]);
              S[b][rt][ct] = MFMA(aqi[rt][kt], bki, S[b][rt][ct]);
            }
          }
      }
      __syncthreads();
    }
  }
  const float fac = 1.0f / 262144.0f;
#pragma unroll
  for (int b = 0; b < 2; ++b) {
    float* dst = scores + ((size_t)(b * 8 + h)) * 4096;
#pragma unroll
    for (int rt = 0; rt < 2; ++rt)
#pragma unroll
      for (int ct = 0; ct < 2; ++ct)
#pragma unroll
        for (int j = 0; j < 4; ++j) {
          int s_ = 32 * wr + rt * 16 + g * 4 + j;
          int t_ = 32 * wc + ct * 16 + r;
          atomicAdd(&dst[s_ * 64 + t_], S[b][rt][ct][j] * fac);
        }
  }
}

// ---------------- K3: log-CPB bias + softmax -> fp16 attn -----------------
__global__ __launch_bounds__(64) void k_softmax(const float* __restrict__ scores,
                                                const float* __restrict__ w1,
                                                const float* __restrict__ b1,
                                                const float* __restrict__ w2,
                                                const float* __restrict__ b2,
                                                f16* __restrict__ at) {
  int id = blockIdx.x;
  int s = id & 63;
  int h = (id >> 6) & 7;
  int t = threadIdx.x;
  float d0 = (float)((s >> 3) - (t >> 3)) * (8.0f / 7.0f);
  float d1 = (float)((s & 7) - (t & 7)) * (8.0f / 7.0f);
  float a0 = log2f(fabsf(d0) + 1.0f) * (1.0f / 3.0f);
  float a1 = log2f(fabsf(d1) + 1.0f) * (1.0f / 3.0f);
  float r0 = (d0 < 0.f) ? -a0 : a0;
  float r1 = (d1 < 0.f) ? -a1 : a1;
  float acc = b2[h];
  for (int c = 0; c < 64; ++c) {
    float hv = fmaf(r0, w1[c], fmaf(r1, w1[64 + c], b1[c]));
    hv = fmaxf(hv, 0.0f);
    acc = fmaf(hv, w2[c * 8 + h], acc);
  }
  float bias = 16.0f / (1.0f + expf(-acc));
  size_t base = (size_t)id * 64;
  float v = scores[base + t] + bias;
  float mx = v;
  for (int o = 32; o; o >>= 1) mx = fmaxf(mx, __shfl_xor(mx, o));
  float e = expf(v - mx);
  float sm = e;
  for (int o = 32; o; o >>= 1) sm += __shfl_xor(sm, o);
  at[base + t] = (f16)(e / sm);
}

// ---------------- K4: MFMA V-path + T14 prefetch -> Ff2[m][...] ------------
__global__ __launch_bounds__(256, 2) void k_vpath_m(
    const f16* __restrict__ Xr, const f16* __restrict__ Xi,
    const f16* __restrict__ Vwr, const f16* __restrict__ Vwi,
    const f16* __restrict__ Owr, const f16* __restrict__ Owi,
    const f16* __restrict__ At, float2* __restrict__ Ff2) {
  __shared__ __align__(16) unsigned char smem[73728];
  const int P_WVR = 0, P_WVI = 8192, P_WOR = 16384, P_WOI = 24576;
  const int P_VTR = 32768, P_VTI = 40960, P_YR = 49152, P_YI = 57344;
  const int P_AT = 65536;
  int tid = threadIdx.x;
  int w = tid >> 6, lane = tid & 63, r = lane & 15, g = lane >> 4;
  int wr = w >> 1, wc = w & 1;
  int id = blockIdx.x;
  int m = ((id >> 4) << 3) + (id & 7);
  int b = (id >> 3) & 1;
  const f16x8* xr8 = (const f16x8*)Xr + (size_t)(b * 256 + m) * 512;
  const f16x8* xi8 = (const f16x8*)Xi + (size_t)(b * 256 + m) * 512;
  f16x8 axr[2][2], axi[2][2], axiN[2][2];
#pragma unroll
  for (int rt = 0; rt < 2; ++rt)
#pragma unroll
    for (int kt = 0; kt < 2; ++kt) {
      int idx = (32 * wr + rt * 16 + r) * 8 + kt * 4 + g;
      axr[rt][kt] = xr8[idx];
      axi[rt][kt] = xi8[idx];
      axiN[rt][kt] = -axi[rt][kt];
    }
  float4 Vst[10];
  auto LOADH = [&](int h) {
    const float4* gvr = (const float4*)Vwr + (size_t)m * 4096 + h * 512;
    const float4* gvi = (const float4*)Vwi + (size_t)m * 4096 + h * 512;
    const float4* gor = (const float4*)Owr + (size_t)m * 4096 + h * 8;
    const float4* goi = (const float4*)Owi + (size_t)m * 4096 + h * 8;
    const float4* gat = (const float4*)At + (size_t)(b * 8 + h) * 512;
    Vst[0] = gvr[tid]; Vst[1] = gvr[tid + 256];
    Vst[2] = gvi[tid]; Vst[3] = gvi[tid + 256];
    int r0_ = tid >> 3, s0_ = tid & 7;
    Vst[4] = gor[r0_ * 64 + s0_]; Vst[5] = gor[(r0_ + 32) * 64 + s0_];
    Vst[6] = goi[r0_ * 64 + s0_]; Vst[7] = goi[(r0_ + 32) * 64 + s0_];
    Vst[8] = gat[tid]; Vst[9] = gat[tid + 256];
  };
  f32x4 fr[2][2] = {}, fi_[2][2] = {};
  LOADH(0);
  for (int h = 0; h < 8; ++h) {
    __syncthreads();  // prev F-GEMM (Y/WO reads) + AT reads complete
#pragma unroll
    for (int it = 0; it < 2; ++it) {
      int s = tid + it * 256;
      int lo = swz128(s >> 3, s & 7);
      *(float4*)(smem + P_WVR + lo) = Vst[0 + it];
      *(float4*)(smem + P_WVI + lo) = Vst[2 + it];
      *(float4*)(smem + P_WOR + lo) = Vst[4 + it];
      *(float4*)(smem + P_WOI + lo) = Vst[6 + it];
      *(float4*)(smem + P_AT + lo) = Vst[8 + it];
    }
    __syncthreads();
    if (h < 7) LOADH(h + 1);  // fly under V/Y/F GEMMs
    // ---- V = X*Wv (mu folded; DC imag exact-zero), store VT[d][t]
    {
      f32x4 vr[2][2] = {}, vi[2][2] = {};
#pragma unroll
      for (int ct = 0; ct < 2; ++ct)
#pragma unroll
        for (int kt = 0; kt < 2; ++kt) {
          int lo = swz128(32 * wc + ct * 16 + r, kt * 4 + g);
          f16x8 bwr = *(const f16x8*)(smem + P_WVR + lo);
          f16x8 bwi = *(const f16x8*)(smem + P_WVI + lo);
#pragma unroll
          for (int rt = 0; rt < 2; ++rt) {
            vr[rt][ct] = MFMA(axr[rt][kt], bwr, vr[rt][ct]);
            vr[rt][ct] = MFMA(axiN[rt][kt], bwi, vr[rt][ct]);
            vi[rt][ct] = MFMA(axr[rt][kt], bwi, vi[rt][ct]);
            vi[rt][ct] = MFMA(axi[rt][kt], bwr, vi[rt][ct]);
          }
        }
#pragma unroll
      for (int rt = 0; rt < 2; ++rt)
#pragma unroll
        for (int ct = 0; ct < 2; ++ct) {
          int drow = 32 * wc + ct * 16 + r;
          int t0 = 32 * wr + rt * 16 + g * 4;
          f16x4 pr, pi;
#pragma unroll
          for (int j = 0; j < 4; ++j) {
            pr[j] = (f16)vr[rt][ct][j];
            pi[j] = (f16)vi[rt][ct][j];
          }
          int lo = swzel(drow, t0);
          *(f16x4*)(smem + P_VTR + lo) = pr;
          *(f16x4*)(smem + P_VTI + lo) = pi;
        }
    }
    __syncthreads();
    // ---- Y = At * V ----
    {
      f16x8 aat[2][2];
#pragma unroll
      for (int rt = 0; rt < 2; ++rt)
#pragma unroll
        for (int kt = 0; kt < 2; ++kt)
          aat[rt][kt] = *(const f16x8*)(
              smem + P_AT + swz128(32 * wr + rt * 16 + r, kt * 4 + g));
      f32x4 yr[2][2] = {}, yi[2][2] = {};
#pragma unroll
      for (int ct = 0; ct < 2; ++ct)
#pragma unroll
        for (int kt = 0; kt < 2; ++kt) {
          int lo = swz128(32 * wc + ct * 16 + r, kt * 4 + g);
          f16x8 bvr = *(const f16x8*)(smem + P_VTR + lo);
          f16x8 bvi = *(const f16x8*)(smem + P_VTI + lo);
#pragma unroll
          for (int rt = 0; rt < 2; ++rt) {
            yr[rt][ct] = MFMA(aat[rt][kt], bvr, yr[rt][ct]);
            yi[rt][ct] = MFMA(aat[rt][kt], bvi, yi[rt][ct]);
          }
        }
#pragma unroll
      for (int rt = 0; rt < 2; ++rt)
#pragma unroll
        for (int ct = 0; ct < 2; ++ct)
#pragma unroll
          for (int j = 0; j < 4; ++j) {
            int row = 32 * wr + rt * 16 + g * 4 + j;
            int col = 32 * wc + ct * 16 + r;
            *(f16*)(smem + P_YR + swzel(row, col)) = (f16)yr[rt][ct][j];
            *(f16*)(smem + P_YI + swzel(row, col)) = (f16)yi[rt][ct][j];
          }
    }
    __syncthreads();
    // ---- F += Y * Wo (complex) ----
    {
      f16x8 ayr[2][2], ayi[2][2], ayiN[2][2];
#pragma unroll
      for (int rt = 0; rt < 2; ++rt)
#pragma unroll
        for (int kt = 0; kt < 2; ++kt) {
          int lo = swz128(32 * wr + rt * 16 + r, kt * 4 + g);
          ayr[rt][kt] = *(const f16x8*)(smem + P_YR + lo);
          ayi[rt][kt] = *(const f16x8*)(smem + P_YI + lo);
          ayiN[rt][kt] = -ayi[rt][kt];
        }
#pragma unroll
      for (int ct = 0; ct < 2; ++ct)
#pragma unroll
        for (int kt = 0; kt < 2; ++kt) {
          int lo = swz128(32 * wc + ct * 16 + r, kt * 4 + g);
          f16x8 bor = *(const f16x8*)(smem + P_WOR + lo);
          f16x8 boi = *(const f16x8*)(smem + P_WOI + lo);
#pragma unroll
          for (int rt = 0; rt < 2; ++rt) {
            fr[rt][ct] = MFMA(ayr[rt][kt], bor, fr[rt][ct]);
            fr[rt][ct] = MFMA(ayiN[rt][kt], boi, fr[rt][ct]);
            fi_[rt][ct] = MFMA(ayr[rt][kt], boi, fi_[rt][ct]);
            fi_[rt][ct] = MFMA(ayi[rt][kt], bor, fi_[rt][ct]);
          }
        }
    }
  }
  float2* dst = Ff2 + (size_t)m * 8192 + (size_t)b * 4096;
#pragma unroll
  for (int rt = 0; rt < 2; ++rt)
#pragma unroll
    for (int ct = 0; ct < 2; ++ct)
#pragma unroll
      for (int j = 0; j < 4; ++j) {
        int s_ = 32 * wr + rt * 16 + g * 4 + j;
        int c_ = 32 * wc + ct * 16 + r;
        dst[s_ * 64 + c_] = make_float2(fr[rt][ct][j], fi_[rt][ct][j]);
      }
}

// ---------------- K5: inverse DFT (reads Ff2[m][f] strided; L2/L3-hit) -----
__global__ __launch_bounds__(256) void k_idft(const float2* __restrict__ Ff2,
                                              float* __restrict__ out) {
  __shared__ float2 Fm[256];
  __shared__ float2 g[32][17];
  __shared__ float2 tw[32];
  int f = blockIdx.x;
  int tid = threadIdx.x;
  if (tid < 32) {
    float a = (2.0f * PI_F / 32.0f) * (float)tid;
    tw[tid] = make_float2(cosf(a), sinf(a));
  }
  Fm[tid] = Ff2[(size_t)tid * 8192 + f];
  __syncthreads();
  for (int o = tid; o < 512; o += 256) {
    int x = o >> 4, q = o & 15;
    float gr = 0.f, gi = 0.f;
#pragma unroll
    for (int p = 0; p < 16; ++p) {
      float2 a = Fm[p * 16 + q];
      float2 w = tw[(p * x) & 31];
      gr += a.x * w.x - a.y * w.y;
      gi += a.x * w.y + a.y * w.x;
    }
    g[x][q] = make_float2(gr, gi);
  }
  __syncthreads();
  int x = tid >> 3, j0 = (tid & 7) * 4;
  float4 r;
  float* rr = &r.x;
#pragma unroll
  for (int jj = 0; jj < 4; ++jj) {
    int j = j0 + jj;
    float acc = 0.f;
#pragma unroll
    for (int q = 0; q < 16; ++q) {
      float2 gv = g[x][q];
      float2 w = tw[(q * j) & 31];
      acc += gv.x * w.x - gv.y * w.y;
    }
    rr[jj] = acc * (1.0f / 1024.0f);
  }
  *(float4*)(out + (size_t)f * 1024 + x * 32 + j0) = r;
}

extern "C" void kernel_launch(void* const* d_in, const int* in_sizes, int n_in,
                              void* d_out, int out_size, void* d_ws,
                              size_t ws_size, hipStream_t stream) {
  const float* seq = (const float*)d_in[0];
  const float2* wq = (const float2*)d_in[1];
  const float2* wk = (const float2*)d_in[2];
  const float2* wv = (const float2*)d_in[3];
  const float2* wo = (const float2*)d_in[4];
  const float* w1 = (const float*)d_in[5];
  const float* b1 = (const float*)d_in[6];
  const float* w2 = (const float*)d_in[7];
  const float* b2 = (const float*)d_in[8];
  float* out = (float*)d_out;

  char* ws = (char*)d_ws;
  f16* Xr = (f16*)(ws + 0);                    //  4 MB
  f16* Xi = (f16*)(ws + 4194304);              //  4 MB
  float* scores = (float*)(ws + 8388608);      //  256 KB
  f16* At = (f16*)(ws + 8650752);              //  128 KB
  float2* Ff2 = (float2*)(ws + 8781824);       //  16 MB [m][f]
  f16* Pqr = (f16*)(ws + 25559040);            //  16.77 MB each
  f16* Pqi = (f16*)(ws + 42336256);
  f16* Pkr = (f16*)(ws + 59113472);
  f16* Pki = (f16*)(ws + 75890688);
  f16* Pvr = (f16*)(ws + 92667904);
  f16* Pvi = (f16*)(ws + 109445120);
  f16* Por = (f16*)(ws + 126222336);
  f16* Poi = (f16*)(ws + 142999552);           // ends 159,776,768

  hipMemsetAsync(scores, 0, 262144, stream);
  k_mega<<<16384, 256, 0, stream>>>(seq, Xr, Xi, wq, wk, wv, wo, Pqr, Pqi,
                                    Pkr, Pki, Pvr, Pvi, Por, Poi);
  k_scores_m<<<dim3(64, 8), 256, 0, stream>>>(Xr, Xi, Pqr, Pqi, Pkr, Pki,
                                              scores);
  k_softmax<<<1024, 64, 0, stream>>>(scores, w1, b1, w2, b2, At);
  k_vpath_m<<<512, 256, 0, stream>>>(Xr, Xi, Pvr, Pvi, Por, Poi, At, Ff2);
  k_idft<<<8192, 256, 0, stream>>>(Ff2, out);
}

// Round 15
// 233.557 us; speedup vs baseline: 1.2760x; 1.2760x over previous
//
#include <hip/hip_runtime.h>
#include <math.h>

// B=2, S=64, C=64, NH=8, H=W=32, M1=M2=16 (256 modes), mode m=p*16+q.
// lambda folded into Pq planes, mu folded into Pv planes (exact pow2 scales);
// DC imag planes of Pq/Pv zeroed (valid since Xi[m=0]==0 exactly).
// R15 = R13 verbatim (revert of R14's refuted prefetch; best measured 233.9us)

#define PI_F 3.14159265358979323846f

typedef _Float16 f16;
typedef f16 f16x8 __attribute__((ext_vector_type(8)));
typedef f16 f16x4 __attribute__((ext_vector_type(4)));
typedef float f32x4 __attribute__((ext_vector_type(4)));

#define MFMA(a, b, c) __builtin_amdgcn_mfma_f32_16x16x32_f16(a, b, c, 0, 0, 0)

__device__ __forceinline__ int swz128(int row, int slot) {
  return (row << 7) + (((slot) ^ (row & 7)) << 4);
}
__device__ __forceinline__ int swzel(int row, int col) {
  return (row << 7) + ((((col) >> 3) ^ (row & 7)) << 4) + (((col) & 7) << 1);
}

// ---------------- dft body (R5-proven) --------------------------------------
__device__ void dft_body(char* sm, int f, int tid, const float* __restrict__ seq,
                         f16* __restrict__ Xr, f16* __restrict__ Xi) {
  float(*fld)[33] = (float(*)[33])sm;            // 4224 B
  float2(*tb)[17] = (float2(*)[17])(sm + 4224);  // 4352 B
  float2* tw = (float2*)(sm + 8576);             // 256 B
  if (tid < 32) {
    float a = (2.0f * PI_F / 32.0f) * (float)tid;
    tw[tid] = make_float2(cosf(a), sinf(a));
  }
  const float4* s4 = (const float4*)(seq + (size_t)f * 1024);
  float4 v = s4[tid];
  int x0 = tid >> 3, y0 = (tid & 7) * 4;
  fld[x0][y0 + 0] = v.x; fld[x0][y0 + 1] = v.y;
  fld[x0][y0 + 2] = v.z; fld[x0][y0 + 3] = v.w;
  __syncthreads();
  for (int o = tid; o < 512; o += 256) {
    int x = o >> 4, q = o & 15;
    float re = 0.f, im = 0.f;
#pragma unroll
    for (int y = 0; y < 32; ++y) {
      float val = fld[x][y];
      float2 w = tw[(q * y) & 31];
      re = fmaf(val, w.x, re);
      im = fmaf(val, -w.y, im);
    }
    tb[x][q] = make_float2(re, im);
  }
  __syncthreads();
  int p = tid >> 4, q = tid & 15;
  float re = 0.f, im = 0.f;
#pragma unroll
  for (int x = 0; x < 32; ++x) {
    float2 t = tb[x][q];
    float2 w = tw[(p * x) & 31];
    re += w.x * t.x + w.y * t.y;
    im += w.x * t.y - w.y * t.x;
  }
  int b = f >> 12;
  int si = f & 4095;
  size_t o = (size_t)(b * 256 + tid) * 4096 + si;
  Xr[o] = (f16)re;
  Xi[o] = (f16)im;
}

// ---------------- repack body (R9: R5 shape + bank swizzle) ----------------
// q/k/v: raw [i(64)][hd(512)][m] -> plane [m][hd*64+i]
// wo:    raw [hd(512)][c(64)][m] -> plane [m][c*512+hd]
__device__ void repack_body(char* sm, int gid, int tid,
                            const float2* __restrict__ wq,
                            const float2* __restrict__ wk,
                            const float2* __restrict__ wv,
                            const float2* __restrict__ wo,
                            f16* __restrict__ Pqr, f16* __restrict__ Pqi,
                            f16* __restrict__ Pkr, f16* __restrict__ Pki,
                            f16* __restrict__ Pvr, f16* __restrict__ Pvi,
                            f16* __restrict__ Por, f16* __restrict__ Poi) {
  f16(*tR)[72] = (f16(*)[72])sm;           // 9216 B
  f16(*tI)[72] = (f16(*)[72])(sm + 9216);  // 9216 B
  int tsel = gid >> 11, r = gid & 2047;
  const float2* in;
  f16 *oR, *oI;
  int m0 = (r & 3) * 64, a0, bb, A, B;
  bool scaled = (tsel == 0) || (tsel == 2);
  if (tsel == 3) {
    in = wo; oR = Por; oI = Poi;
    a0 = ((r >> 2) & 7) * 64; bb = r >> 5; A = 512; B = 64;
  } else {
    a0 = 0; bb = r >> 2; A = 64; B = 512;
    in = (tsel == 0) ? wq : (tsel == 1) ? wk : wv;
    oR = (tsel == 0) ? Pqr : (tsel == 1) ? Pkr : Pvr;
    oI = (tsel == 0) ? Pqi : (tsel == 1) ? Pki : Pvi;
  }
  const float4* in4 = (const float4*)in;
  for (int k = tid; k < 2048; k += 256) {
    int ai = k >> 5, mj = k & 31;
    float4 v = in4[((size_t)(a0 + ai) * B + bb) * 128 + (m0 >> 1) + mj];
    int sw = (mj & 7) << 3;
    tR[2 * mj + 0][ai ^ sw] = (f16)v.x;
    tI[2 * mj + 0][ai ^ sw] = (f16)v.y;
    tR[2 * mj + 1][ai ^ sw] = (f16)v.z;
    tI[2 * mj + 1][ai ^ sw] = (f16)v.w;
  }
  __syncthreads();
  for (int k = tid; k < 1024; k += 256) {
    int pl = k >> 9, s = k & 511;
    int mi = s >> 3, a8 = (s & 7) * 8;
    int sw = ((mi >> 1) & 7) << 3;
    f16x8 v = pl ? *(const f16x8*)&tI[mi][a8 ^ sw]
                 : *(const f16x8*)&tR[mi][a8 ^ sw];
    int mode = m0 + mi;
    if (scaled) {
      f16 scl = (mode == 0) ? (f16)1.0f
                            : (((mode & 15) == 0) ? (f16)0.5f : (f16)2.0f);
      v = v * scl;
      if (pl && mode == 0) v = (f16x8)(f16)0.0f;
    }
    f16* dst = pl ? oI : oR;
    *(f16x8*)&dst[(size_t)mode * 32768 + (size_t)bb * A + a0 + a8] = v;
  }
}

// ---------------- K-mega: repack (identity order) ∪ dft --------------------
__global__ __launch_bounds__(256) void k_mega(
    const float* __restrict__ seq, f16* __restrict__ Xr, f16* __restrict__ Xi,
    const float2* __restrict__ wq, const float2* __restrict__ wk,
    const float2* __restrict__ wv, const float2* __restrict__ wo,
    f16* __restrict__ Pqr, f16* __restrict__ Pqi, f16* __restrict__ Pkr,
    f16* __restrict__ Pki, f16* __restrict__ Pvr, f16* __restrict__ Pvi,
    f16* __restrict__ Por, f16* __restrict__ Poi) {
  __shared__ __align__(16) char sm[18432];
  int bx = blockIdx.x, tid = threadIdx.x;
  if (bx < 8192) {
    repack_body(sm, bx, tid, wq, wk, wv, wo, Pqr, Pqi, Pkr, Pki, Pvr, Pvi,
                Por, Poi);
  } else {
    dft_body(sm, bx - 8192, tid, seq, Xr, Xi);
  }
}

// ---------------- K2: MFMA scores, b-merged (chunk=4, grid 64x8) -----------
__global__ __launch_bounds__(256, 2) void k_scores_m(
    const f16* __restrict__ Xr, const f16* __restrict__ Xi,
    const f16* __restrict__ Qwr, const f16* __restrict__ Qwi,
    const f16* __restrict__ Kwr, const f16* __restrict__ Kwi,
    float* __restrict__ scores) {
  __shared__ __align__(16) unsigned char smem[65536];
  const int P_WQR = 0, P_WQI = 8192, P_WKR = 16384, P_WKI = 24576;
  const int P_QR = 32768, P_QI = 40960, P_KR = 49152, P_KI = 57344;
  int tid = threadIdx.x;
  int w = tid >> 6, lane = tid & 63, r = lane & 15, g = lane >> 4;
  int wr = w >> 1, wc = w & 1;
  int chunk = blockIdx.x, h = blockIdx.y;
  f32x4 S[2][2][2] = {};  // [b][rt][ct]
  for (int mm = 0; mm < 4; ++mm) {
    int m = chunk * 4 + mm;
    const float4* gqr = (const float4*)Qwr + (size_t)m * 4096 + h * 512;
    const float4* gqi = (const float4*)Qwi + (size_t)m * 4096 + h * 512;
    const float4* gkr = (const float4*)Kwr + (size_t)m * 4096 + h * 512;
    const float4* gki = (const float4*)Kwi + (size_t)m * 4096 + h * 512;
#pragma unroll
    for (int it = 0; it < 2; ++it) {
      int s = tid + it * 256;
      int lo = swz128(s >> 3, s & 7);
      *(float4*)(smem + P_WQR + lo) = gqr[s];
      *(float4*)(smem + P_WQI + lo) = gqi[s];
      *(float4*)(smem + P_WKR + lo) = gkr[s];
      *(float4*)(smem + P_WKI + lo) = gki[s];
    }
    __syncthreads();
#pragma unroll
    for (int b = 0; b < 2; ++b) {
      const f16x8* xr8 = (const f16x8*)Xr + (size_t)(b * 256 + m) * 512;
      const f16x8* xi8 = (const f16x8*)Xi + (size_t)(b * 256 + m) * 512;
      f16x8 axr[2][2], axi[2][2];
#pragma unroll
      for (int rt = 0; rt < 2; ++rt)
#pragma unroll
        for (int kt = 0; kt < 2; ++kt) {
          int idx = (32 * wr + rt * 16 + r) * 8 + kt * 4 + g;
          axr[rt][kt] = xr8[idx];
          axi[rt][kt] = xi8[idx];
        }
      // ---- Q = X*Wq (lambda pre-folded; DC imag exact-zero) ----
      {
        f32x4 cr[2][2] = {}, ci[2][2] = {};
#pragma unroll
        for (int ct = 0; ct < 2; ++ct)
#pragma unroll
          for (int kt = 0; kt < 2; ++kt) {
            int lo = swz128(32 * wc + ct * 16 + r, kt * 4 + g);
            f16x8 bwr = *(const f16x8*)(smem + P_WQR + lo);
            f16x8 bwi = *(const f16x8*)(smem + P_WQI + lo);
            f16x8 bwiN = -bwi;
#pragma unroll
            for (int rt = 0; rt < 2; ++rt) {
              cr[rt][ct] = MFMA(axr[rt][kt], bwr, cr[rt][ct]);
              cr[rt][ct] = MFMA(axi[rt][kt], bwiN, cr[rt][ct]);
              ci[rt][ct] = MFMA(axr[rt][kt], bwi, ci[rt][ct]);
              ci[rt][ct] = MFMA(axi[rt][kt], bwr, ci[rt][ct]);
            }
          }
#pragma unroll
        for (int rt = 0; rt < 2; ++rt)
#pragma unroll
          for (int ct = 0; ct < 2; ++ct)
#pragma unroll
            for (int j = 0; j < 4; ++j) {
              int row = 32 * wr + rt * 16 + g * 4 + j;
              int col = 32 * wc + ct * 16 + r;
              *(f16*)(smem + P_QR + swzel(row, col)) = (f16)cr[rt][ct][j];
              *(f16*)(smem + P_QI + swzel(row, col)) = (f16)ci[rt][ct][j];
            }
      }
      // ---- K = X*Wk ----
      {
        f32x4 cr[2][2] = {}, ci[2][2] = {};
#pragma unroll
        for (int ct = 0; ct < 2; ++ct)
#pragma unroll
          for (int kt = 0; kt < 2; ++kt) {
            int lo = swz128(32 * wc + ct * 16 + r, kt * 4 + g);
            f16x8 bwr = *(const f16x8*)(smem + P_WKR + lo);
            f16x8 bwi = *(const f16x8*)(smem + P_WKI + lo);
            f16x8 bwiN = -bwi;
#pragma unroll
            for (int rt = 0; rt < 2; ++rt) {
              cr[rt][ct] = MFMA(axr[rt][kt], bwr, cr[rt][ct]);
              cr[rt][ct] = MFMA(axi[rt][kt], bwiN, cr[rt][ct]);
              ci[rt][ct] = MFMA(axr[rt][kt], bwi, ci[rt][ct]);
              ci[rt][ct] = MFMA(axi[rt][kt], bwr, ci[rt][ct]);
            }
          }
#pragma unroll
        for (int rt = 0; rt < 2; ++rt)
#pragma unroll
          for (int ct = 0; ct < 2; ++ct)
#pragma unroll
            for (int j = 0; j < 4; ++j) {
              int row = 32 * wr + rt * 16 + g * 4 + j;
              int col = 32 * wc + ct * 16 + r;
              *(f16*)(smem + P_KR + swzel(row, col)) = (f16)cr[rt][ct][j];
              *(f16*)(smem + P_KI + swzel(row, col)) = (f16)ci[rt][ct][j];
            }
      }
      __syncthreads();
      // ---- S[b] += Qr*Kr^T + Qi*Ki^T ----
      {
        f16x8 aqr[2][2], aqi[2][2];
#pragma unroll
        for (int rt = 0; rt < 2; ++rt)
#pragma unroll
          for (int kt = 0; kt < 2; ++kt) {
            int lo = swz128(32 * wr + rt * 16 + r, kt * 4 + g);
            aqr[rt][kt] = *(const f16x8*)(smem + P_QR + lo);
            aqi[rt][kt] = *(const f16x8*)(smem + P_QI + lo);
          }
#pragma unroll
        for (int ct = 0; ct < 2; ++ct)
#pragma unroll
          for (int kt = 0; kt < 2; ++kt) {
            int lo = swz128(32 * wc + ct * 16 + r, kt * 4 + g);
            f16x8 bkr = *(const f16x8*)(smem + P_KR + lo);
            f16x8 bki = *(const f16x8*)(smem + P_KI + lo);
#pragma unroll
            for (int rt = 0; rt < 2; ++rt) {
              S[b][rt][ct] = MFMA(aqr[rt][kt], bkr, S[b][rt][ct]);
              S[b][rt][ct] = MFMA(aqi[rt][kt], bki, S[b][rt][ct]);
            }
          }
      }
      __syncthreads();
    }
  }
  const float fac = 1.0f / 262144.0f;
#pragma unroll
  for (int b = 0; b < 2; ++b) {
    float* dst = scores + ((size_t)(b * 8 + h)) * 4096;
#pragma unroll
    for (int rt = 0; rt < 2; ++rt)
#pragma unroll
      for (int ct = 0; ct < 2; ++ct)
#pragma unroll
        for (int j = 0; j < 4; ++j) {
          int s_ = 32 * wr + rt * 16 + g * 4 + j;
          int t_ = 32 * wc + ct * 16 + r;
          atomicAdd(&dst[s_ * 64 + t_], S[b][rt][ct][j] * fac);
        }
  }
}

// ---------------- K3: log-CPB bias + softmax -> fp16 attn -----------------
__global__ __launch_bounds__(64) void k_softmax(const float* __restrict__ scores,
                                                const float* __restrict__ w1,
                                                const float* __restrict__ b1,
                                                const float* __restrict__ w2,
                                                const float* __restrict__ b2,
                                                f16* __restrict__ at) {
  int id = blockIdx.x;
  int s = id & 63;
  int h = (id >> 6) & 7;
  int t = threadIdx.x;
  float d0 = (float)((s >> 3) - (t >> 3)) * (8.0f / 7.0f);
  float d1 = (float)((s & 7) - (t & 7)) * (8.0f / 7.0f);
  float a0 = log2f(fabsf(d0) + 1.0f) * (1.0f / 3.0f);
  float a1 = log2f(fabsf(d1) + 1.0f) * (1.0f / 3.0f);
  float r0 = (d0 < 0.f) ? -a0 : a0;
  float r1 = (d1 < 0.f) ? -a1 : a1;
  float acc = b2[h];
  for (int c = 0; c < 64; ++c) {
    float hv = fmaf(r0, w1[c], fmaf(r1, w1[64 + c], b1[c]));
    hv = fmaxf(hv, 0.0f);
    acc = fmaf(hv, w2[c * 8 + h], acc);
  }
  float bias = 16.0f / (1.0f + expf(-acc));
  size_t base = (size_t)id * 64;
  float v = scores[base + t] + bias;
  float mx = v;
  for (int o = 32; o; o >>= 1) mx = fmaxf(mx, __shfl_xor(mx, o));
  float e = expf(v - mx);
  float sm = e;
  for (int o = 32; o; o >>= 1) sm += __shfl_xor(sm, o);
  at[base + t] = (f16)(e / sm);
}

// ---------------- K4: MFMA V-path -> coalesced Ff2[m][b*4096+s*64+c] -------
__global__ __launch_bounds__(256, 2) void k_vpath_m(
    const f16* __restrict__ Xr, const f16* __restrict__ Xi,
    const f16* __restrict__ Vwr, const f16* __restrict__ Vwi,
    const f16* __restrict__ Owr, const f16* __restrict__ Owi,
    const f16* __restrict__ At, float2* __restrict__ Ff2) {
  __shared__ __align__(16) unsigned char smem[73728];
  const int P_WVR = 0, P_WVI = 8192, P_WOR = 16384, P_WOI = 24576;
  const int P_VTR = 32768, P_VTI = 40960, P_YR = 49152, P_YI = 57344;
  const int P_AT = 65536;
  int tid = threadIdx.x;
  int w = tid >> 6, lane = tid & 63, r = lane & 15, g = lane >> 4;
  int wr = w >> 1, wc = w & 1;
  int id = blockIdx.x;
  int m = ((id >> 4) << 3) + (id & 7);
  int b = (id >> 3) & 1;
  const f16x8* xr8 = (const f16x8*)Xr + (size_t)(b * 256 + m) * 512;
  const f16x8* xi8 = (const f16x8*)Xi + (size_t)(b * 256 + m) * 512;
  f16x8 axr[2][2], axi[2][2], axiN[2][2];
#pragma unroll
  for (int rt = 0; rt < 2; ++rt)
#pragma unroll
    for (int kt = 0; kt < 2; ++kt) {
      int idx = (32 * wr + rt * 16 + r) * 8 + kt * 4 + g;
      axr[rt][kt] = xr8[idx];
      axi[rt][kt] = xi8[idx];
      axiN[rt][kt] = -axi[rt][kt];
    }
  f32x4 fr[2][2] = {}, fi_[2][2] = {};
  for (int h = 0; h < 8; ++h) {
    __syncthreads();
    const float4* gvr = (const float4*)Vwr + (size_t)m * 4096 + h * 512;
    const float4* gvi = (const float4*)Vwi + (size_t)m * 4096 + h * 512;
    const float4* gor = (const float4*)Owr + (size_t)m * 4096 + h * 8;
    const float4* goi = (const float4*)Owi + (size_t)m * 4096 + h * 8;
    const float4* gat = (const float4*)At + (size_t)(b * 8 + h) * 512;
#pragma unroll
    for (int it = 0; it < 2; ++it) {
      int s = tid + it * 256;
      int row = s >> 3, sl = s & 7;
      int lo = swz128(row, sl);
      *(float4*)(smem + P_WVR + lo) = gvr[s];
      *(float4*)(smem + P_WVI + lo) = gvi[s];
      *(float4*)(smem + P_WOR + lo) = gor[row * 64 + sl];
      *(float4*)(smem + P_WOI + lo) = goi[row * 64 + sl];
      *(float4*)(smem + P_AT + lo) = gat[s];
    }
    __syncthreads();
    // ---- V = X*Wv (mu folded; DC imag exact-zero), store VT[d][t]
    {
      f32x4 vr[2][2] = {}, vi[2][2] = {};
#pragma unroll
      for (int ct = 0; ct < 2; ++ct)
#pragma unroll
        for (int kt = 0; kt < 2; ++kt) {
          int lo = swz128(32 * wc + ct * 16 + r, kt * 4 + g);
          f16x8 bwr = *(const f16x8*)(smem + P_WVR + lo);
          f16x8 bwi = *(const f16x8*)(smem + P_WVI + lo);
#pragma unroll
          for (int rt = 0; rt < 2; ++rt) {
            vr[rt][ct] = MFMA(axr[rt][kt], bwr, vr[rt][ct]);
            vr[rt][ct] = MFMA(axiN[rt][kt], bwi, vr[rt][ct]);
            vi[rt][ct] = MFMA(axr[rt][kt], bwi, vi[rt][ct]);
            vi[rt][ct] = MFMA(axi[rt][kt], bwr, vi[rt][ct]);
          }
        }
#pragma unroll
      for (int rt = 0; rt < 2; ++rt)
#pragma unroll
        for (int ct = 0; ct < 2; ++ct) {
          int drow = 32 * wc + ct * 16 + r;
          int t0 = 32 * wr + rt * 16 + g * 4;
          f16x4 pr, pi;
#pragma unroll
          for (int j = 0; j < 4; ++j) {
            pr[j] = (f16)vr[rt][ct][j];
            pi[j] = (f16)vi[rt][ct][j];
          }
          int lo = swzel(drow, t0);
          *(f16x4*)(smem + P_VTR + lo) = pr;
          *(f16x4*)(smem + P_VTI + lo) = pi;
        }
    }
    __syncthreads();
    // ---- Y = At * V ----
    {
      f16x8 aat[2][2];
#pragma unroll
      for (int rt = 0; rt < 2; ++rt)
#pragma unroll
        for (int kt = 0; kt < 2; ++kt)
          aat[rt][kt] = *(const f16x8*)(
              smem + P_AT + swz128(32 * wr + rt * 16 + r, kt * 4 + g));
      f32x4 yr[2][2] = {}, yi[2][2] = {};
#pragma unroll
      for (int ct = 0; ct < 2; ++ct)
#pragma unroll
        for (int kt = 0; kt < 2; ++kt) {
          int lo = swz128(32 * wc + ct * 16 + r, kt * 4 + g);
          f16x8 bvr = *(const f16x8*)(smem + P_VTR + lo);
          f16x8 bvi = *(const f16x8*)(smem + P_VTI + lo);
#pragma unroll
          for (int rt = 0; rt < 2; ++rt) {
            yr[rt][ct] = MFMA(aat[rt][kt], bvr, yr[rt][ct]);
            yi[rt][ct] = MFMA(aat[rt][kt], bvi, yi[rt][ct]);
          }
        }
#pragma unroll
      for (int rt = 0; rt < 2; ++rt)
#pragma unroll
        for (int ct = 0; ct < 2; ++ct)
#pragma unroll
          for (int j = 0; j < 4; ++j) {
            int row = 32 * wr + rt * 16 + g * 4 + j;
            int col = 32 * wc + ct * 16 + r;
            *(f16*)(smem + P_YR + swzel(row, col)) = (f16)yr[rt][ct][j];
            *(f16*)(smem + P_YI + swzel(row, col)) = (f16)yi[rt][ct][j];
          }
    }
    __syncthreads();
    // ---- F += Y * Wo (complex) ----
    {
      f16x8 ayr[2][2], ayi[2][2], ayiN[2][2];
#pragma unroll
      for (int rt = 0; rt < 2; ++rt)
#pragma unroll
        for (int kt = 0; kt < 2; ++kt) {
          int lo = swz128(32 * wr + rt * 16 + r, kt * 4 + g);
          ayr[rt][kt] = *(const f16x8*)(smem + P_YR + lo);
          ayi[rt][kt] = *(const f16x8*)(smem + P_YI + lo);
          ayiN[rt][kt] = -ayi[rt][kt];
        }
#pragma unroll
      for (int ct = 0; ct < 2; ++ct)
#pragma unroll
        for (int kt = 0; kt < 2; ++kt) {
          int lo = swz128(32 * wc + ct * 16 + r, kt * 4 + g);
          f16x8 bor = *(const f16x8*)(smem + P_WOR + lo);
          f16x8 boi = *(const f16x8*)(smem + P_WOI + lo);
#pragma unroll
          for (int rt = 0; rt < 2; ++rt) {
            fr[rt][ct] = MFMA(ayr[rt][kt], bor, fr[rt][ct]);
            fr[rt][ct] = MFMA(ayiN[rt][kt], boi, fr[rt][ct]);
            fi_[rt][ct] = MFMA(ayr[rt][kt], boi, fi_[rt][ct]);
            fi_[rt][ct] = MFMA(ayi[rt][kt], bor, fi_[rt][ct]);
          }
        }
    }
  }
  float2* dst = Ff2 + (size_t)m * 8192 + (size_t)b * 4096;
#pragma unroll
  for (int rt = 0; rt < 2; ++rt)
#pragma unroll
    for (int ct = 0; ct < 2; ++ct)
#pragma unroll
      for (int j = 0; j < 4; ++j) {
        int s_ = 32 * wr + rt * 16 + g * 4 + j;
        int c_ = 32 * wc + ct * 16 + r;
        dst[s_ * 64 + c_] = make_float2(fr[rt][ct][j], fi_[rt][ct][j]);
      }
}

// ---------------- K5: inverse DFT (reads Ff2[m][f] strided; L2/L3-hit) -----
__global__ __launch_bounds__(256) void k_idft(const float2* __restrict__ Ff2,
                                              float* __restrict__ out) {
  __shared__ float2 Fm[256];
  __shared__ float2 g[32][17];
  __shared__ float2 tw[32];
  int f = blockIdx.x;
  int tid = threadIdx.x;
  if (tid < 32) {
    float a = (2.0f * PI_F / 32.0f) * (float)tid;
    tw[tid] = make_float2(cosf(a), sinf(a));
  }
  Fm[tid] = Ff2[(size_t)tid * 8192 + f];
  __syncthreads();
  for (int o = tid; o < 512; o += 256) {
    int x = o >> 4, q = o & 15;
    float gr = 0.f, gi = 0.f;
#pragma unroll
    for (int p = 0; p < 16; ++p) {
      float2 a = Fm[p * 16 + q];
      float2 w = tw[(p * x) & 31];
      gr += a.x * w.x - a.y * w.y;
      gi += a.x * w.y + a.y * w.x;
    }
    g[x][q] = make_float2(gr, gi);
  }
  __syncthreads();
  int x = tid >> 3, j0 = (tid & 7) * 4;
  float4 r;
  float* rr = &r.x;
#pragma unroll
  for (int jj = 0; jj < 4; ++jj) {
    int j = j0 + jj;
    float acc = 0.f;
#pragma unroll
    for (int q = 0; q < 16; ++q) {
      float2 gv = g[x][q];
      float2 w = tw[(q * j) & 31];
      acc += gv.x * w.x - gv.y * w.y;
    }
    rr[jj] = acc * (1.0f / 1024.0f);
  }
  *(float4*)(out + (size_t)f * 1024 + x * 32 + j0) = r;
}

extern "C" void kernel_launch(void* const* d_in, const int* in_sizes, int n_in,
                              void* d_out, int out_size, void* d_ws,
                              size_t ws_size, hipStream_t stream) {
  const float* seq = (const float*)d_in[0];
  const float2* wq = (const float2*)d_in[1];
  const float2* wk = (const float2*)d_in[2];
  const float2* wv = (const float2*)d_in[3];
  const float2* wo = (const float2*)d_in[4];
  const float* w1 = (const float*)d_in[5];
  const float* b1 = (const float*)d_in[6];
  const float* w2 = (const float*)d_in[7];
  const float* b2 = (const float*)d_in[8];
  float* out = (float*)d_out;

  char* ws = (char*)d_ws;
  f16* Xr = (f16*)(ws + 0);                    //  4 MB
  f16* Xi = (f16*)(ws + 4194304);              //  4 MB
  float* scores = (float*)(ws + 8388608);      //  256 KB
  f16* At = (f16*)(ws + 8650752);              //  128 KB
  float2* Ff2 = (float2*)(ws + 8781824);       //  16 MB [m][f]
  f16* Pqr = (f16*)(ws + 25559040);            //  16.77 MB each
  f16* Pqi = (f16*)(ws + 42336256);
  f16* Pkr = (f16*)(ws + 59113472);
  f16* Pki = (f16*)(ws + 75890688);
  f16* Pvr = (f16*)(ws + 92667904);
  f16* Pvi = (f16*)(ws + 109445120);
  f16* Por = (f16*)(ws + 126222336);
  f16* Poi = (f16*)(ws + 142999552);           // ends 159,776,768

  hipMemsetAsync(scores, 0, 262144, stream);
  k_mega<<<16384, 256, 0, stream>>>(seq, Xr, Xi, wq, wk, wv, wo, Pqr, Pqi,
                                    Pkr, Pki, Pvr, Pvi, Por, Poi);
  k_scores_m<<<dim3(64, 8), 256, 0, stream>>>(Xr, Xi, Pqr, Pqi, Pkr, Pki,
                                              scores);
  k_softmax<<<1024, 64, 0, stream>>>(scores, w1, b1, w2, b2, At);
  k_vpath_m<<<512, 256, 0, stream>>>(Xr, Xi, Pvr, Pvi, Por, Poi, At, Ff2);
  k_idft<<<8192, 256, 0, stream>>>(Ff2, out);
}